// Round 9
// baseline (237.110 us; speedup 1.0000x reference)
//
#include <hip/hip_runtime.h>
#include <hip/hip_bf16.h>
#include <math.h>

// Problem constants
#define BQ 4
#define NQ 100
#define MQ 50
#define HWSZ 65536
#define NP 112   // padded N rows in partials (7 x 16)
#define MP 64    // padded M (4 x 16)
#define BK 32    // K depth (f32 elems) per pipeline step (one 16x16x32 MFMA K)
#define DCLAMP 13.8155106f   // logit(1-1e-6) = -logit(1e-6)
#define LOG2E   1.44269504f
#define LN2     0.69314718f

typedef __attribute__((ext_vector_type(8))) short short8;
typedef __attribute__((ext_vector_type(4))) float f32x4;

// pack two floats -> two bf16 (RTNE) in one u32
__device__ __forceinline__ unsigned pk2(float a, float b) {
    __hip_bfloat162 h = __float22bfloat162_rn(float2{a, b});
    unsigned u; __builtin_memcpy(&u, &h, 4); return u;
}

// build a bf16x8 MFMA fragment from 8 consecutive floats (two float4)
__device__ __forceinline__ short8 mk8(float4 a, float4 b) {
    union { short8 s; unsigned u[4]; } r;
    r.u[0] = pk2(a.x, a.y); r.u[1] = pk2(a.z, a.w);
    r.u[2] = pk2(b.x, b.y); r.u[3] = pk2(b.z, b.w);
    return r.s;
}

__device__ __forceinline__ float sum8(float4 a, float4 b) {
    return (a.x + a.y) + (a.z + a.w) + ((b.x + b.y) + (b.z + b.w));
}

#define MFMA16(A, B, C) __builtin_amdgcn_mfma_f32_16x16x32_bf16(A, B, C, 0, 0, 0)

// ---------------- packed-path transform: raw v_exp/v_log (base-2 HW ops) ----
// d = clamp(x); e = 2^(xc*log2e) = e^xc; r = rcp(1+e); pm = 1-r (= sigmoid(xc));
// l2m = log2(r) = -log2(1+e)  (accumulated; multiplied by ln2 once at the end).
__device__ __forceinline__ void xform2b(float x, float& d, float& pm, float& l2m) {
    float xc = fminf(fmaxf(x, -DCLAMP), DCLAMP);
    d = xc;
    float e = __builtin_amdgcn_exp2f(xc * LOG2E);   // v_exp_f32: 2^x
    float r = __builtin_amdgcn_rcpf(1.0f + e);
    pm = 1.0f - r;
    l2m = __builtin_amdgcn_logf(r);                 // v_log_f32: log2(x)
}

__device__ __forceinline__ void xf8b(float4 u, float4 v, short8& fd, short8& fp,
                                     float& rsl2, float& rsp) {
    float d0,d1,d2,d3,d4,d5,d6,d7, p0,p1,p2,p3,p4,p5,p6,p7, l;
    xform2b(u.x, d0, p0, l); rsl2 += l;
    xform2b(u.y, d1, p1, l); rsl2 += l;
    xform2b(u.z, d2, p2, l); rsl2 += l;
    xform2b(u.w, d3, p3, l); rsl2 += l;
    xform2b(v.x, d4, p4, l); rsl2 += l;
    xform2b(v.y, d5, p5, l); rsl2 += l;
    xform2b(v.z, d6, p6, l); rsl2 += l;
    xform2b(v.w, d7, p7, l); rsl2 += l;
    rsp += (p0 + p1) + (p2 + p3) + ((p4 + p5) + (p6 + p7));
    union { short8 s; unsigned w[4]; } rd, rp;
    rd.w[0] = pk2(d0, d1); rd.w[1] = pk2(d2, d3); rd.w[2] = pk2(d4, d5); rd.w[3] = pk2(d6, d7);
    rp.w[0] = pk2(p0, p1); rp.w[1] = pk2(p2, p3); rp.w[2] = pk2(p4, p5); rp.w[3] = pk2(p6, p7);
    fd = rd.s; fp = rp.s;
}

// ---------------- fallback-path transform (R7 verbatim) ---------------------
__device__ __forceinline__ void xform2(float x, float& d, float& pm, float& l1m) {
    float xc = fminf(fmaxf(x, -DCLAMP), DCLAMP);
    d = xc;
    float e = __expf(xc);
    float r = __builtin_amdgcn_rcpf(1.0f + e);
    pm = e * r;
    l1m = -__logf(1.0f + e);
}
__device__ __forceinline__ void xf8(float4 u, float4 v, short8& fd, short8& fp,
                                    float& rsl, float& rsp) {
    float d0,d1,d2,d3,d4,d5,d6,d7, p0,p1,p2,p3,p4,p5,p6,p7, l;
    xform2(u.x, d0, p0, l); rsl += l;
    xform2(u.y, d1, p1, l); rsl += l;
    xform2(u.z, d2, p2, l); rsl += l;
    xform2(u.w, d3, p3, l); rsl += l;
    xform2(v.x, d4, p4, l); rsl += l;
    xform2(v.y, d5, p5, l); rsl += l;
    xform2(v.z, d6, p6, l); rsl += l;
    xform2(v.w, d7, p7, l); rsl += l;
    rsp += (p0 + p1) + (p2 + p3) + ((p4 + p5) + (p6 + p7));
    union { short8 s; unsigned w[4]; } rd, rp;
    rd.w[0] = pk2(d0, d1); rd.w[1] = pk2(d2, d3); rd.w[2] = pk2(d4, d5); rd.w[3] = pk2(d6, d7);
    rp.w[0] = pk2(p0, p1); rp.w[1] = pk2(p2, p3); rp.w[2] = pk2(p4, p5); rp.w[3] = pk2(p6, p7);
    fd = rd.s; fp = rp.s;
}

// ======================= pack kernel (packed path) ===========================
// grid (nch, BQ), 256 threads. Block (chunk,b): converts tgt_masks chunk to
// bf16 in operand-ready row-major layout bpack[b][m][k] (m<50 only; m>=50
// handled by row-clamp in main, garbage cols never read) and computes tm
// column sums per chunk into tspart (m>=50 slots = 0).
__global__ __launch_bounds__(256)
void pack_b(const float* __restrict__ tgt_masks, unsigned short* __restrict__ bpack,
            float* __restrict__ tspart, int nch, int Kc)
{
    const int chunk = blockIdx.x, b = blockIdx.y;
    const int m = threadIdx.x >> 2;     // 0..63
    const int q = threadIdx.x & 3;
    float ts = 0.f;
    if (m < MQ) {
        const float* src = tgt_masks + (((long)(b * MQ + m)) << 16) + (long)chunk * Kc;
        unsigned short* dst = bpack + (((long)(b * MQ + m)) << 16) + (long)chunk * Kc;
        for (int k = q * 4; k < Kc; k += 16) {
            const float4 v = *(const float4*)(src + k);
            ts += (v.x + v.y) + (v.z + v.w);
            union { ushort4 s; uint2 u; } o;
            o.u.x = pk2(v.x, v.y); o.u.y = pk2(v.z, v.w);
            *(ushort4*)(dst + k) = o.s;
        }
    }
    ts += __shfl_down(ts, 1);
    ts += __shfl_down(ts, 2);
    if (q == 0)
        tspart[(long)(b * nch + chunk) * MP + m] = (m < MQ) ? ts : 0.f;
}

// ===================== packed main kernel (barrier-free) =====================
// grid = 2*G blocks, G = BQ*nch. Blocks g and G+g handle the same (b,chunk)
// and land on the same XCD under round-robin dispatch -> B re-reads hit
// XCD-local L2. h=0: nt=wave (0..3); h=1: nt=4+wave (wave 3 exits).
// B: pre-packed bf16 fragments, 4 x 16B loads/step, depth-2 prefetch, 0 VALU.
// A: f32 loads in operand layout, depth-2 prefetch, in-register transform.
__global__ __launch_bounds__(256)
void matcher_main_packed(const float* __restrict__ pred_masks,
                         const unsigned short* __restrict__ bpack,
                         float* __restrict__ part1, float* __restrict__ part2,
                         float* __restrict__ rspart, int nch, int Kc)
{
    const int G = BQ * nch;
    const int g = blockIdx.x % G;
    const int h = blockIdx.x / G;
    const int w = threadIdx.x >> 6;
    const int nt = h * 4 + w;
    if (nt >= 7) return;                 // wave-uniform exit
    const int b = g / nch, chunk = g % nch;
    const int l = threadIdx.x & 63;
    const int m15 = l & 15;
    const int ks8 = (l >> 4) * 8;
    const long kb = (long)chunk * Kc;
    const int nsteps = Kc / BK;          // even

    const int arow = min(nt * 16 + m15, NQ - 1);
    const float* pa = pred_masks + (((long)(b * NQ + arow)) << 16) + kb + ks8;
    const unsigned short* pb0 = bpack + (((long)(b * MQ + min( 0 + m15, MQ - 1))) << 16) + kb + ks8;
    const unsigned short* pb1 = bpack + (((long)(b * MQ + min(16 + m15, MQ - 1))) << 16) + kb + ks8;
    const unsigned short* pb2 = bpack + (((long)(b * MQ + min(32 + m15, MQ - 1))) << 16) + kb + ks8;
    const unsigned short* pb3 = bpack + (((long)(b * MQ + min(48 + m15, MQ - 1))) << 16) + kb + ks8;

    f32x4 acc1[4], acc2[4];
    #pragma unroll
    for (int i = 0; i < 4; i++) { acc1[i] = (f32x4){0.f,0.f,0.f,0.f}; acc2[i] = (f32x4){0.f,0.f,0.f,0.f}; }
    float rsl2 = 0.f, rsp = 0.f;

    // prologue: issue B(0),B(1),A(0),A(1)  (named register sets, depth 2)
    short8 B00 = *(const short8*)pb0, B01 = *(const short8*)pb1,
           B02 = *(const short8*)pb2, B03 = *(const short8*)pb3;
    short8 B10 = *(const short8*)(pb0 + BK), B11 = *(const short8*)(pb1 + BK),
           B12 = *(const short8*)(pb2 + BK), B13 = *(const short8*)(pb3 + BK);
    pb0 += 2 * BK; pb1 += 2 * BK; pb2 += 2 * BK; pb3 += 2 * BK;
    float4 a0x = *(const float4*)(pa),      a0y = *(const float4*)(pa + 4);
    float4 a1x = *(const float4*)(pa + BK), a1y = *(const float4*)(pa + BK + 4);
    pa += 2 * BK;

    for (int s = 0; s < nsteps; s += 2) {
        // ---- even step: consume A0/B0*, refill for s+2 ----
        {
            short8 fd, fp;
            xf8b(a0x, a0y, fd, fp, rsl2, rsp);
            const short8 bf0 = B00, bf1 = B01, bf2 = B02, bf3 = B03;
            if (s + 2 < nsteps) {
                a0x = *(const float4*)(pa); a0y = *(const float4*)(pa + 4); pa += BK;
                B00 = *(const short8*)pb0; B01 = *(const short8*)pb1;
                B02 = *(const short8*)pb2; B03 = *(const short8*)pb3;
                pb0 += BK; pb1 += BK; pb2 += BK; pb3 += BK;
            }
            acc1[0] = MFMA16(fd, bf0, acc1[0]); acc2[0] = MFMA16(fp, bf0, acc2[0]);
            acc1[1] = MFMA16(fd, bf1, acc1[1]); acc2[1] = MFMA16(fp, bf1, acc2[1]);
            acc1[2] = MFMA16(fd, bf2, acc1[2]); acc2[2] = MFMA16(fp, bf2, acc2[2]);
            acc1[3] = MFMA16(fd, bf3, acc1[3]); acc2[3] = MFMA16(fp, bf3, acc2[3]);
        }
        // ---- odd step: consume A1/B1*, refill for s+3 ----
        {
            short8 fd, fp;
            xf8b(a1x, a1y, fd, fp, rsl2, rsp);
            const short8 bf0 = B10, bf1 = B11, bf2 = B12, bf3 = B13;
            if (s + 3 < nsteps) {
                a1x = *(const float4*)(pa); a1y = *(const float4*)(pa + 4); pa += BK;
                B10 = *(const short8*)pb0; B11 = *(const short8*)pb1;
                B12 = *(const short8*)pb2; B13 = *(const short8*)pb3;
                pb0 += BK; pb1 += BK; pb2 += BK; pb3 += BK;
            }
            acc1[0] = MFMA16(fd, bf0, acc1[0]); acc2[0] = MFMA16(fp, bf0, acc2[0]);
            acc1[1] = MFMA16(fd, bf1, acc1[1]); acc2[1] = MFMA16(fp, bf1, acc2[1]);
            acc1[2] = MFMA16(fd, bf2, acc1[2]); acc2[2] = MFMA16(fp, bf2, acc2[2]);
            acc1[3] = MFMA16(fd, bf3, acc1[3]); acc2[3] = MFMA16(fp, bf3, acc2[3]);
        }
    }

    // ---- store C partials: C/D layout col=lane&15, row=(lane>>4)*4+reg ----
    const long pbase = ((long)(b * nch + chunk)) * NP * MP;
    const int nr0 = (l >> 4) * 4;
    #pragma unroll
    for (int mt = 0; mt < 4; ++mt) {
        #pragma unroll
        for (int rr = 0; rr < 4; ++rr) {
            const int ng = nt * 16 + nr0 + rr;
            part1[pbase + ng * MP + mt * 16 + m15] = acc1[mt][rr];
            part2[pbase + ng * MP + mt * 16 + m15] = acc2[mt][rr];
        }
    }

    // ---- row sums: lanes {m,m+16,m+32,m+48} hold row m's k-slices ----
    float rsl = rsl2 * LN2;
    rsl += __shfl_xor(rsl, 16); rsl += __shfl_xor(rsl, 32);
    rsp += __shfl_xor(rsp, 16); rsp += __shfl_xor(rsp, 32);
    if (l < 16) {
        const long rb = ((long)(b * nch + chunk) * NP + nt * 16 + l) * 2;
        rspart[rb + 0] = rsl;
        rspart[rb + 1] = rsp;
    }
}

// ===================== fallback main kernel (R7 verbatim) ====================
__global__ __launch_bounds__(256)
void matcher_main(const float* __restrict__ pred_masks,
                  const float* __restrict__ tgt_masks,
                  float* __restrict__ part1, float* __restrict__ part2,
                  float* __restrict__ rspart, float* __restrict__ tspart,
                  int nch, int Kc)
{
    const int wj = blockIdx.x * 4 + (threadIdx.x >> 6);
    const int l  = threadIdx.x & 63;
    const int jb = nch * 7;
    const int b  = wj / jb;
    const int r  = wj % jb;
    const int chunk = r / 7;
    const int nt    = r % 7;
    const int m15 = l & 15;
    const int ks8 = (l >> 4) * 8;
    const long kb = (long)chunk * Kc;
    const int nsteps = Kc / BK;

    const int arow = min(nt * 16 + m15, NQ - 1);
    const float* pa = pred_masks + (((long)(b * NQ + arow)) << 16) + kb + ks8;
    const float* pb0 = tgt_masks + (((long)(b * MQ + min( 0 + m15, MQ - 1))) << 16) + kb + ks8;
    const float* pb1 = tgt_masks + (((long)(b * MQ + min(16 + m15, MQ - 1))) << 16) + kb + ks8;
    const float* pb2 = tgt_masks + (((long)(b * MQ + min(32 + m15, MQ - 1))) << 16) + kb + ks8;
    const float* pb3 = tgt_masks + (((long)(b * MQ + min(48 + m15, MQ - 1))) << 16) + kb + ks8;

    f32x4 acc1[4], acc2[4];
    #pragma unroll
    for (int i = 0; i < 4; i++) { acc1[i] = (f32x4){0.f,0.f,0.f,0.f}; acc2[i] = (f32x4){0.f,0.f,0.f,0.f}; }
    float rsl = 0.f, rsp = 0.f;
    float ts0 = 0.f, ts1 = 0.f, ts2 = 0.f, ts3 = 0.f;
    const bool do_ts = (nt == 0);

    float4 b00 = *(const float4*)(pb0), b01 = *(const float4*)(pb0 + 4);
    float4 b10 = *(const float4*)(pb1), b11 = *(const float4*)(pb1 + 4);
    float4 b20 = *(const float4*)(pb2), b21 = *(const float4*)(pb2 + 4);
    float4 b30 = *(const float4*)(pb3), b31 = *(const float4*)(pb3 + 4);
    float4 a0x = *(const float4*)(pa),      a0y = *(const float4*)(pa + 4);
    float4 a1x = *(const float4*)(pa + BK), a1y = *(const float4*)(pa + BK + 4);
    pa += 2 * BK;

    for (int s = 0; s < nsteps; s += 2) {
        {
            const short8 bf0 = mk8(b00, b01), bf1 = mk8(b10, b11);
            const short8 bf2 = mk8(b20, b21), bf3 = mk8(b30, b31);
            if (do_ts) { ts0 += sum8(b00, b01); ts1 += sum8(b10, b11);
                         ts2 += sum8(b20, b21); ts3 += sum8(b30, b31); }
            if (s + 1 < nsteps) {
                pb0 += BK; pb1 += BK; pb2 += BK; pb3 += BK;
                b00 = *(const float4*)(pb0); b01 = *(const float4*)(pb0 + 4);
                b10 = *(const float4*)(pb1); b11 = *(const float4*)(pb1 + 4);
                b20 = *(const float4*)(pb2); b21 = *(const float4*)(pb2 + 4);
                b30 = *(const float4*)(pb3); b31 = *(const float4*)(pb3 + 4);
            }
            short8 fd, fp;
            xf8(a0x, a0y, fd, fp, rsl, rsp);
            if (s + 2 < nsteps) { a0x = *(const float4*)(pa); a0y = *(const float4*)(pa + 4); pa += BK; }
            acc1[0] = MFMA16(fd, bf0, acc1[0]); acc2[0] = MFMA16(fp, bf0, acc2[0]);
            acc1[1] = MFMA16(fd, bf1, acc1[1]); acc2[1] = MFMA16(fp, bf1, acc2[1]);
            acc1[2] = MFMA16(fd, bf2, acc1[2]); acc2[2] = MFMA16(fp, bf2, acc2[2]);
            acc1[3] = MFMA16(fd, bf3, acc1[3]); acc2[3] = MFMA16(fp, bf3, acc2[3]);
        }
        {
            const short8 bf0 = mk8(b00, b01), bf1 = mk8(b10, b11);
            const short8 bf2 = mk8(b20, b21), bf3 = mk8(b30, b31);
            if (do_ts) { ts0 += sum8(b00, b01); ts1 += sum8(b10, b11);
                         ts2 += sum8(b20, b21); ts3 += sum8(b30, b31); }
            if (s + 2 < nsteps) {
                pb0 += BK; pb1 += BK; pb2 += BK; pb3 += BK;
                b00 = *(const float4*)(pb0); b01 = *(const float4*)(pb0 + 4);
                b10 = *(const float4*)(pb1); b11 = *(const float4*)(pb1 + 4);
                b20 = *(const float4*)(pb2); b21 = *(const float4*)(pb2 + 4);
                b30 = *(const float4*)(pb3); b31 = *(const float4*)(pb3 + 4);
            }
            short8 fd, fp;
            xf8(a1x, a1y, fd, fp, rsl, rsp);
            if (s + 3 < nsteps) { a1x = *(const float4*)(pa); a1y = *(const float4*)(pa + 4); pa += BK; }
            acc1[0] = MFMA16(fd, bf0, acc1[0]); acc2[0] = MFMA16(fp, bf0, acc2[0]);
            acc1[1] = MFMA16(fd, bf1, acc1[1]); acc2[1] = MFMA16(fp, bf1, acc2[1]);
            acc1[2] = MFMA16(fd, bf2, acc1[2]); acc2[2] = MFMA16(fp, bf2, acc2[2]);
            acc1[3] = MFMA16(fd, bf3, acc1[3]); acc2[3] = MFMA16(fp, bf3, acc2[3]);
        }
    }

    const long pbase = ((long)(b * nch + chunk)) * NP * MP;
    const int nr0 = (l >> 4) * 4;
    #pragma unroll
    for (int mt = 0; mt < 4; ++mt) {
        #pragma unroll
        for (int rr = 0; rr < 4; ++rr) {
            const int ng = nt * 16 + nr0 + rr;
            part1[pbase + ng * MP + mt * 16 + m15] = acc1[mt][rr];
            part2[pbase + ng * MP + mt * 16 + m15] = acc2[mt][rr];
        }
    }

    rsl += __shfl_xor(rsl, 16); rsl += __shfl_xor(rsl, 32);
    rsp += __shfl_xor(rsp, 16); rsp += __shfl_xor(rsp, 32);
    if (l < 16) {
        const long rb = ((long)(b * nch + chunk) * NP + nt * 16 + l) * 2;
        rspart[rb + 0] = rsl;
        rspart[rb + 1] = rsp;
    }
    if (do_ts) {
        ts0 += __shfl_xor(ts0, 16); ts0 += __shfl_xor(ts0, 32);
        ts1 += __shfl_xor(ts1, 16); ts1 += __shfl_xor(ts1, 32);
        ts2 += __shfl_xor(ts2, 16); ts2 += __shfl_xor(ts2, 32);
        ts3 += __shfl_xor(ts3, 16); ts3 += __shfl_xor(ts3, 32);
        if (l < 16) {
            const long tb = (long)(b * nch + chunk) * MP;
            tspart[tb +  0 + l] = ts0;
            tspart[tb + 16 + l] = ts1;
            tspart[tb + 32 + l] = ts2;
            tspart[tb + 48 + l] = ts3;
        }
    }
}

// ============================ epilogue (shared) ==============================
__global__ __launch_bounds__(1024)
void matcher_epilogue(const float* __restrict__ pred_logits,
                      const float* __restrict__ pred_style,
                      const int*   __restrict__ styles,
                      const float* __restrict__ part1,
                      const float* __restrict__ part2,
                      const float* __restrict__ rspart,
                      const float* __restrict__ tspart,
                      float* __restrict__ out, int nch)
{
    __shared__ float red1[16][64], red2[16][64], redt[16][64];
    __shared__ float slw[16], spw[16];

    const int blk = blockIdx.x;
    const int b = blk / NQ, n = blk % NQ;
    const int t = threadIdx.x;
    const int m = t & 63, cg = t >> 6;

    float S1 = 0.f, S2 = 0.f, St = 0.f;
    for (int c = cg; c < nch; c += 16) {
        const long base = ((long)(b * nch + c) * NP + n) * MP + m;
        S1 += part1[base];
        S2 += part2[base];
        St += tspart[(long)(b * nch + c) * MP + m];
    }
    red1[cg][m] = S1; red2[cg][m] = S2; redt[cg][m] = St;

    float sl = 0.f, sp = 0.f;
    if (t < nch) {
        const float2 v = *(const float2*)&rspart[((long)(b * nch + t) * NP + n) * 2];
        sl = v.x; sp = v.y;
    }
    #pragma unroll
    for (int off = 32; off; off >>= 1) { sl += __shfl_down(sl, off); sp += __shfl_down(sp, off); }
    if ((t & 63) == 0) { slw[t >> 6] = sl; spw[t >> 6] = sp; }
    __syncthreads();

    if (t < MQ) {
        float Sl = 0.f, Sp = 0.f, s1 = 0.f, s2 = 0.f, st = 0.f;
        #pragma unroll
        for (int ww = 0; ww < 16; ww++) {
            Sl += slw[ww]; Sp += spw[ww];
            s1 += red1[ww][t]; s2 += red2[ww][t]; st += redt[ww][t];
        }

        const float l0 = pred_logits[(b * NQ + n) * 2 + 0];
        const float l1 = pred_logits[(b * NQ + n) * 2 + 1];
        const float p1 = 1.0f / (1.0f + __expf(l0 - l1));

        const float* stp = &pred_style[(b * NQ + n) * 4];
        const float v0 = stp[0], v1 = stp[1], v2 = stp[2], v3 = stp[3];
        const float mx = fmaxf(fmaxf(v0, v1), fmaxf(v2, v3));
        const float e0 = __expf(v0 - mx), e1 = __expf(v1 - mx),
                    e2 = __expf(v2 - mx), e3 = __expf(v3 - mx);
        const float esum = e0 + e1 + e2 + e3;
        int sid = styles[b * MQ + t];
        sid = min(max(sid, 0), 3);
        const float ps = (sid == 0 ? e0 : sid == 1 ? e1 : sid == 2 ? e2 : e3) / esum;

        const float cost_mask = -(s1 + Sl) * (1.0f / (float)HWSZ);
        const float dice = 1.0f - (2.0f * s2 + 1.0f) / (Sp + st + 1.0f);

        float c = 2.0f * (-p1) + 5.0f * cost_mask + 5.0f * dice + 1.0f * (-ps);
        if (isnan(c)) c = 10000.0f;
        else if (isinf(c)) c = (c > 0.f) ? 10000.0f : -10000.0f;
        out[(b * NQ + n) * MQ + t] = c;
    }
}

extern "C" void kernel_launch(void* const* d_in, const int* in_sizes, int n_in,
                              void* d_out, int out_size, void* d_ws, size_t ws_size,
                              hipStream_t stream) {
    const float* pred_logits = (const float*)d_in[0];
    const float* pred_masks  = (const float*)d_in[1];
    const float* pred_style  = (const float*)d_in[2];
    const float* tgt_masks   = (const float*)d_in[3];
    const int*   styles      = (const int*)d_in[4];
    float* out = (float*)d_out;

    const size_t packB_elems = (size_t)BQ * MQ * HWSZ;           // bf16 elems
    const size_t packB_bytes = packB_elems * 2;                  // 26.2 MB
    auto need = [](int c) {
        return (size_t)c * (2ull * BQ * NP * MP * 4ull
                            + (size_t)BQ * NP * 2 * 4ull
                            + (size_t)BQ * MP * 4ull);
    };

    int nch = 0; bool use_packed = false;
    for (int cand = 128; cand >= 64; cand >>= 1)
        if (need(cand) + packB_bytes <= ws_size) { nch = cand; use_packed = true; break; }
    if (!use_packed)
        for (int cand = 128; cand >= 8; cand >>= 1)
            if (need(cand) <= ws_size) { nch = cand; break; }
    const int Kc = HWSZ / nch;

    float* part1  = (float*)d_ws;
    float* part2  = part1 + (size_t)BQ * nch * NP * MP;
    float* rspart = part2 + (size_t)BQ * nch * NP * MP;
    float* tspart = rspart + (size_t)BQ * nch * NP * 2;
    unsigned short* bpack = (unsigned short*)(tspart + (size_t)BQ * nch * MP);

    if (use_packed) {
        pack_b<<<dim3(nch, BQ), 256, 0, stream>>>(tgt_masks, bpack, tspart, nch, Kc);
        matcher_main_packed<<<2 * BQ * nch, 256, 0, stream>>>(
            pred_masks, bpack, part1, part2, rspart, nch, Kc);
    } else {
        matcher_main<<<nch * 7, 256, 0, stream>>>(
            pred_masks, tgt_masks, part1, part2, rspart, tspart, nch, Kc);
    }

    matcher_epilogue<<<BQ * NQ, 1024, 0, stream>>>(
        pred_logits, pred_style, styles, part1, part2, rspart, tspart, out, nch);
}

// Round 10
// 233.602 us; speedup vs baseline: 1.0150x; 1.0150x over previous
//
#include <hip/hip_runtime.h>
#include <hip/hip_bf16.h>
#include <math.h>

// Problem constants
#define BQ 4
#define NQ 100
#define MQ 50
#define HWSZ 65536
#define NP 112   // padded N rows in partials (7 x 16)
#define MP 64    // padded M (4 x 16)
#define BK 32    // K depth (f32 elems) per pipeline step (one 16x16x32 MFMA K)
#define DCLAMP 13.8155106f   // logit(1-1e-6) = -logit(1e-6)
#define LOG2E   1.44269504f
#define LN2     0.69314718f

typedef __attribute__((ext_vector_type(8))) short short8;
typedef __attribute__((ext_vector_type(4))) float f32x4;

// pack two floats -> two bf16 (RTNE) in one u32
__device__ __forceinline__ unsigned pk2(float a, float b) {
    __hip_bfloat162 h = __float22bfloat162_rn(float2{a, b});
    unsigned u; __builtin_memcpy(&u, &h, 4); return u;
}

// build a bf16x8 MFMA fragment from 8 consecutive floats (two float4)
__device__ __forceinline__ short8 mk8(float4 a, float4 b) {
    union { short8 s; unsigned u[4]; } r;
    r.u[0] = pk2(a.x, a.y); r.u[1] = pk2(a.z, a.w);
    r.u[2] = pk2(b.x, b.y); r.u[3] = pk2(b.z, b.w);
    return r.s;
}

__device__ __forceinline__ float sum8(float4 a, float4 b) {
    return (a.x + a.y) + (a.z + a.w) + ((b.x + b.y) + (b.z + b.w));
}

#define MFMA16(A, B, C) __builtin_amdgcn_mfma_f32_16x16x32_bf16(A, B, C, 0, 0, 0)

// ---------------- packed-path transform: raw v_exp/v_log (base-2 HW ops) ----
// d = clamp(x); e = 2^(xc*log2e) = e^xc; r = rcp(1+e); pm = 1-r (= sigmoid(xc));
// l2m = log2(r) = -log2(1+e)  (accumulated; multiplied by ln2 once at the end).
__device__ __forceinline__ void xform2b(float x, float& d, float& pm, float& l2m) {
    float xc = fminf(fmaxf(x, -DCLAMP), DCLAMP);
    d = xc;
    float e = __builtin_amdgcn_exp2f(xc * LOG2E);   // v_exp_f32: 2^x
    float r = __builtin_amdgcn_rcpf(1.0f + e);
    pm = 1.0f - r;
    l2m = __builtin_amdgcn_logf(r);                 // v_log_f32: log2(x)
}

__device__ __forceinline__ void xf8b(float4 u, float4 v, short8& fd, short8& fp,
                                     float& rsl2, float& rsp) {
    float d0,d1,d2,d3,d4,d5,d6,d7, p0,p1,p2,p3,p4,p5,p6,p7, l;
    xform2b(u.x, d0, p0, l); rsl2 += l;
    xform2b(u.y, d1, p1, l); rsl2 += l;
    xform2b(u.z, d2, p2, l); rsl2 += l;
    xform2b(u.w, d3, p3, l); rsl2 += l;
    xform2b(v.x, d4, p4, l); rsl2 += l;
    xform2b(v.y, d5, p5, l); rsl2 += l;
    xform2b(v.z, d6, p6, l); rsl2 += l;
    xform2b(v.w, d7, p7, l); rsl2 += l;
    rsp += (p0 + p1) + (p2 + p3) + ((p4 + p5) + (p6 + p7));
    union { short8 s; unsigned w[4]; } rd, rp;
    rd.w[0] = pk2(d0, d1); rd.w[1] = pk2(d2, d3); rd.w[2] = pk2(d4, d5); rd.w[3] = pk2(d6, d7);
    rp.w[0] = pk2(p0, p1); rp.w[1] = pk2(p2, p3); rp.w[2] = pk2(p4, p5); rp.w[3] = pk2(p6, p7);
    fd = rd.s; fp = rp.s;
}

// ---------------- fallback-path transform (R7 verbatim) ---------------------
__device__ __forceinline__ void xform2(float x, float& d, float& pm, float& l1m) {
    float xc = fminf(fmaxf(x, -DCLAMP), DCLAMP);
    d = xc;
    float e = __expf(xc);
    float r = __builtin_amdgcn_rcpf(1.0f + e);
    pm = e * r;
    l1m = -__logf(1.0f + e);
}
__device__ __forceinline__ void xf8(float4 u, float4 v, short8& fd, short8& fp,
                                    float& rsl, float& rsp) {
    float d0,d1,d2,d3,d4,d5,d6,d7, p0,p1,p2,p3,p4,p5,p6,p7, l;
    xform2(u.x, d0, p0, l); rsl += l;
    xform2(u.y, d1, p1, l); rsl += l;
    xform2(u.z, d2, p2, l); rsl += l;
    xform2(u.w, d3, p3, l); rsl += l;
    xform2(v.x, d4, p4, l); rsl += l;
    xform2(v.y, d5, p5, l); rsl += l;
    xform2(v.z, d6, p6, l); rsl += l;
    xform2(v.w, d7, p7, l); rsl += l;
    rsp += (p0 + p1) + (p2 + p3) + ((p4 + p5) + (p6 + p7));
    union { short8 s; unsigned w[4]; } rd, rp;
    rd.w[0] = pk2(d0, d1); rd.w[1] = pk2(d2, d3); rd.w[2] = pk2(d4, d5); rd.w[3] = pk2(d6, d7);
    rp.w[0] = pk2(p0, p1); rp.w[1] = pk2(p2, p3); rp.w[2] = pk2(p4, p5); rp.w[3] = pk2(p6, p7);
    fd = rd.s; fp = rp.s;
}

// ======================= pack kernel (packed path) ===========================
__global__ __launch_bounds__(256)
void pack_b(const float* __restrict__ tgt_masks, unsigned short* __restrict__ bpack,
            float* __restrict__ tspart, int nch, int Kc)
{
    const int chunk = blockIdx.x, b = blockIdx.y;
    const int m = threadIdx.x >> 2;     // 0..63
    const int q = threadIdx.x & 3;
    float ts = 0.f;
    if (m < MQ) {
        const float* src = tgt_masks + (((long)(b * MQ + m)) << 16) + (long)chunk * Kc;
        unsigned short* dst = bpack + (((long)(b * MQ + m)) << 16) + (long)chunk * Kc;
        for (int k = q * 4; k < Kc; k += 16) {
            const float4 v = *(const float4*)(src + k);
            ts += (v.x + v.y) + (v.z + v.w);
            union { ushort4 s; uint2 u; } o;
            o.u.x = pk2(v.x, v.y); o.u.y = pk2(v.z, v.w);
            *(ushort4*)(dst + k) = o.s;
        }
    }
    ts += __shfl_down(ts, 1);
    ts += __shfl_down(ts, 2);
    if (q == 0)
        tspart[(long)(b * nch + chunk) * MP + m] = (m < MQ) ? ts : 0.f;
}

// ------------- one pipeline step (named regs only; A depth-4, B depth-2) -----
// Consumes A set (ax,ay) and B parity set (Bb0..3); refills them for steps
// s+4 / s+2 via the monotonically-advancing shared pointers. A issued before B
// so A-waits never drain same-iteration B loads.
__device__ __forceinline__ void pstep(
    float4& ax, float4& ay,
    short8& Bb0, short8& Bb1, short8& Bb2, short8& Bb3,
    const float*& pa,
    const unsigned short*& pb0, const unsigned short*& pb1,
    const unsigned short*& pb2, const unsigned short*& pb3,
    bool pfA, bool pfB,
    f32x4 (&acc1)[4], f32x4 (&acc2)[4], float& rsl2, float& rsp)
{
    short8 fd, fp;
    xf8b(ax, ay, fd, fp, rsl2, rsp);
    const short8 bf0 = Bb0, bf1 = Bb1, bf2 = Bb2, bf3 = Bb3;
    if (pfA) { ax = *(const float4*)pa; ay = *(const float4*)(pa + 4); pa += BK; }
    if (pfB) {
        Bb0 = *(const short8*)pb0; Bb1 = *(const short8*)pb1;
        Bb2 = *(const short8*)pb2; Bb3 = *(const short8*)pb3;
        pb0 += BK; pb1 += BK; pb2 += BK; pb3 += BK;
    }
    acc1[0] = MFMA16(fd, bf0, acc1[0]); acc2[0] = MFMA16(fp, bf0, acc2[0]);
    acc1[1] = MFMA16(fd, bf1, acc1[1]); acc2[1] = MFMA16(fp, bf1, acc2[1]);
    acc1[2] = MFMA16(fd, bf2, acc1[2]); acc2[2] = MFMA16(fp, bf2, acc2[2]);
    acc1[3] = MFMA16(fd, bf3, acc1[3]); acc2[3] = MFMA16(fp, bf3, acc2[3]);
}

// ===================== packed main kernel (barrier-free) =====================
// grid = 2*G, G = BQ*nch. One wave = one (b,chunk,nt) job, fully independent.
// A: f32 operand-layout loads, DEPTH-4 register prefetch (4 named sets).
// B: pre-packed bf16 fragments, 4 x 16B loads/step, depth-2 prefetch, 0 VALU.
__global__ __launch_bounds__(256)
void matcher_main_packed(const float* __restrict__ pred_masks,
                         const unsigned short* __restrict__ bpack,
                         float* __restrict__ part1, float* __restrict__ part2,
                         float* __restrict__ rspart, int nch, int Kc)
{
    const int G = BQ * nch;
    const int g = blockIdx.x % G;
    const int h = blockIdx.x / G;
    const int w = threadIdx.x >> 6;
    const int nt = h * 4 + w;
    if (nt >= 7) return;                 // wave-uniform exit
    const int b = g / nch, chunk = g % nch;
    const int l = threadIdx.x & 63;
    const int m15 = l & 15;
    const int ks8 = (l >> 4) * 8;
    const long kb = (long)chunk * Kc;
    const int nsteps = Kc / BK;          // multiple of 4 (nch in {64,128})

    const int arow = min(nt * 16 + m15, NQ - 1);
    const float* pa = pred_masks + (((long)(b * NQ + arow)) << 16) + kb + ks8;
    const unsigned short* pb0 = bpack + (((long)(b * MQ + min( 0 + m15, MQ - 1))) << 16) + kb + ks8;
    const unsigned short* pb1 = bpack + (((long)(b * MQ + min(16 + m15, MQ - 1))) << 16) + kb + ks8;
    const unsigned short* pb2 = bpack + (((long)(b * MQ + min(32 + m15, MQ - 1))) << 16) + kb + ks8;
    const unsigned short* pb3 = bpack + (((long)(b * MQ + min(48 + m15, MQ - 1))) << 16) + kb + ks8;

    f32x4 acc1[4], acc2[4];
    #pragma unroll
    for (int i = 0; i < 4; i++) { acc1[i] = (f32x4){0.f,0.f,0.f,0.f}; acc2[i] = (f32x4){0.f,0.f,0.f,0.f}; }
    float rsl2 = 0.f, rsp = 0.f;

    // prologue: issue A(0..3) first (4 named sets), then B(0),B(1) (2 parities)
    float4 a0x = *(const float4*)(pa),          a0y = *(const float4*)(pa + 4);
    float4 a1x = *(const float4*)(pa + BK),     a1y = *(const float4*)(pa + BK + 4);
    float4 a2x = *(const float4*)(pa + 2 * BK), a2y = *(const float4*)(pa + 2 * BK + 4);
    float4 a3x = *(const float4*)(pa + 3 * BK), a3y = *(const float4*)(pa + 3 * BK + 4);
    pa += 4 * BK;
    short8 B00 = *(const short8*)pb0, B01 = *(const short8*)pb1,
           B02 = *(const short8*)pb2, B03 = *(const short8*)pb3;
    short8 B10 = *(const short8*)(pb0 + BK), B11 = *(const short8*)(pb1 + BK),
           B12 = *(const short8*)(pb2 + BK), B13 = *(const short8*)(pb3 + BK);
    pb0 += 2 * BK; pb1 += 2 * BK; pb2 += 2 * BK; pb3 += 2 * BK;

    for (int s = 0; s < nsteps; s += 4) {
        pstep(a0x, a0y, B00, B01, B02, B03, pa, pb0, pb1, pb2, pb3,
              s + 4 < nsteps, s + 2 < nsteps, acc1, acc2, rsl2, rsp);
        pstep(a1x, a1y, B10, B11, B12, B13, pa, pb0, pb1, pb2, pb3,
              s + 5 < nsteps, s + 3 < nsteps, acc1, acc2, rsl2, rsp);
        pstep(a2x, a2y, B00, B01, B02, B03, pa, pb0, pb1, pb2, pb3,
              s + 6 < nsteps, s + 4 < nsteps, acc1, acc2, rsl2, rsp);
        pstep(a3x, a3y, B10, B11, B12, B13, pa, pb0, pb1, pb2, pb3,
              s + 7 < nsteps, s + 5 < nsteps, acc1, acc2, rsl2, rsp);
    }

    // ---- store C partials: C/D layout col=lane&15, row=(lane>>4)*4+reg ----
    const long pbase = ((long)(b * nch + chunk)) * NP * MP;
    const int nr0 = (l >> 4) * 4;
    #pragma unroll
    for (int mt = 0; mt < 4; ++mt) {
        #pragma unroll
        for (int rr = 0; rr < 4; ++rr) {
            const int ng = nt * 16 + nr0 + rr;
            part1[pbase + ng * MP + mt * 16 + m15] = acc1[mt][rr];
            part2[pbase + ng * MP + mt * 16 + m15] = acc2[mt][rr];
        }
    }

    // ---- row sums: lanes {m,m+16,m+32,m+48} hold row m's k-slices ----
    float rsl = rsl2 * LN2;
    rsl += __shfl_xor(rsl, 16); rsl += __shfl_xor(rsl, 32);
    rsp += __shfl_xor(rsp, 16); rsp += __shfl_xor(rsp, 32);
    if (l < 16) {
        const long rb = ((long)(b * nch + chunk) * NP + nt * 16 + l) * 2;
        rspart[rb + 0] = rsl;
        rspart[rb + 1] = rsp;
    }
}

// ===================== fallback main kernel (R7 verbatim) ====================
__global__ __launch_bounds__(256)
void matcher_main(const float* __restrict__ pred_masks,
                  const float* __restrict__ tgt_masks,
                  float* __restrict__ part1, float* __restrict__ part2,
                  float* __restrict__ rspart, float* __restrict__ tspart,
                  int nch, int Kc)
{
    const int wj = blockIdx.x * 4 + (threadIdx.x >> 6);
    const int l  = threadIdx.x & 63;
    const int jb = nch * 7;
    const int b  = wj / jb;
    const int r  = wj % jb;
    const int chunk = r / 7;
    const int nt    = r % 7;
    const int m15 = l & 15;
    const int ks8 = (l >> 4) * 8;
    const long kb = (long)chunk * Kc;
    const int nsteps = Kc / BK;

    const int arow = min(nt * 16 + m15, NQ - 1);
    const float* pa = pred_masks + (((long)(b * NQ + arow)) << 16) + kb + ks8;
    const float* pb0 = tgt_masks + (((long)(b * MQ + min( 0 + m15, MQ - 1))) << 16) + kb + ks8;
    const float* pb1 = tgt_masks + (((long)(b * MQ + min(16 + m15, MQ - 1))) << 16) + kb + ks8;
    const float* pb2 = tgt_masks + (((long)(b * MQ + min(32 + m15, MQ - 1))) << 16) + kb + ks8;
    const float* pb3 = tgt_masks + (((long)(b * MQ + min(48 + m15, MQ - 1))) << 16) + kb + ks8;

    f32x4 acc1[4], acc2[4];
    #pragma unroll
    for (int i = 0; i < 4; i++) { acc1[i] = (f32x4){0.f,0.f,0.f,0.f}; acc2[i] = (f32x4){0.f,0.f,0.f,0.f}; }
    float rsl = 0.f, rsp = 0.f;
    float ts0 = 0.f, ts1 = 0.f, ts2 = 0.f, ts3 = 0.f;
    const bool do_ts = (nt == 0);

    float4 b00 = *(const float4*)(pb0), b01 = *(const float4*)(pb0 + 4);
    float4 b10 = *(const float4*)(pb1), b11 = *(const float4*)(pb1 + 4);
    float4 b20 = *(const float4*)(pb2), b21 = *(const float4*)(pb2 + 4);
    float4 b30 = *(const float4*)(pb3), b31 = *(const float4*)(pb3 + 4);
    float4 a0x = *(const float4*)(pa),      a0y = *(const float4*)(pa + 4);
    float4 a1x = *(const float4*)(pa + BK), a1y = *(const float4*)(pa + BK + 4);
    pa += 2 * BK;

    for (int s = 0; s < nsteps; s += 2) {
        {
            const short8 bf0 = mk8(b00, b01), bf1 = mk8(b10, b11);
            const short8 bf2 = mk8(b20, b21), bf3 = mk8(b30, b31);
            if (do_ts) { ts0 += sum8(b00, b01); ts1 += sum8(b10, b11);
                         ts2 += sum8(b20, b21); ts3 += sum8(b30, b31); }
            if (s + 1 < nsteps) {
                pb0 += BK; pb1 += BK; pb2 += BK; pb3 += BK;
                b00 = *(const float4*)(pb0); b01 = *(const float4*)(pb0 + 4);
                b10 = *(const float4*)(pb1); b11 = *(const float4*)(pb1 + 4);
                b20 = *(const float4*)(pb2); b21 = *(const float4*)(pb2 + 4);
                b30 = *(const float4*)(pb3); b31 = *(const float4*)(pb3 + 4);
            }
            short8 fd, fp;
            xf8(a0x, a0y, fd, fp, rsl, rsp);
            if (s + 2 < nsteps) { a0x = *(const float4*)(pa); a0y = *(const float4*)(pa + 4); pa += BK; }
            acc1[0] = MFMA16(fd, bf0, acc1[0]); acc2[0] = MFMA16(fp, bf0, acc2[0]);
            acc1[1] = MFMA16(fd, bf1, acc1[1]); acc2[1] = MFMA16(fp, bf1, acc2[1]);
            acc1[2] = MFMA16(fd, bf2, acc1[2]); acc2[2] = MFMA16(fp, bf2, acc2[2]);
            acc1[3] = MFMA16(fd, bf3, acc1[3]); acc2[3] = MFMA16(fp, bf3, acc2[3]);
        }
        {
            const short8 bf0 = mk8(b00, b01), bf1 = mk8(b10, b11);
            const short8 bf2 = mk8(b20, b21), bf3 = mk8(b30, b31);
            if (do_ts) { ts0 += sum8(b00, b01); ts1 += sum8(b10, b11);
                         ts2 += sum8(b20, b21); ts3 += sum8(b30, b31); }
            if (s + 2 < nsteps) {
                pb0 += BK; pb1 += BK; pb2 += BK; pb3 += BK;
                b00 = *(const float4*)(pb0); b01 = *(const float4*)(pb0 + 4);
                b10 = *(const float4*)(pb1); b11 = *(const float4*)(pb1 + 4);
                b20 = *(const float4*)(pb2); b21 = *(const float4*)(pb2 + 4);
                b30 = *(const float4*)(pb3); b31 = *(const float4*)(pb3 + 4);
            }
            short8 fd, fp;
            xf8(a1x, a1y, fd, fp, rsl, rsp);
            if (s + 3 < nsteps) { a1x = *(const float4*)(pa); a1y = *(const float4*)(pa + 4); pa += BK; }
            acc1[0] = MFMA16(fd, bf0, acc1[0]); acc2[0] = MFMA16(fp, bf0, acc2[0]);
            acc1[1] = MFMA16(fd, bf1, acc1[1]); acc2[1] = MFMA16(fp, bf1, acc2[1]);
            acc1[2] = MFMA16(fd, bf2, acc1[2]); acc2[2] = MFMA16(fp, bf2, acc2[2]);
            acc1[3] = MFMA16(fd, bf3, acc1[3]); acc2[3] = MFMA16(fp, bf3, acc2[3]);
        }
    }

    const long pbase = ((long)(b * nch + chunk)) * NP * MP;
    const int nr0 = (l >> 4) * 4;
    #pragma unroll
    for (int mt = 0; mt < 4; ++mt) {
        #pragma unroll
        for (int rr = 0; rr < 4; ++rr) {
            const int ng = nt * 16 + nr0 + rr;
            part1[pbase + ng * MP + mt * 16 + m15] = acc1[mt][rr];
            part2[pbase + ng * MP + mt * 16 + m15] = acc2[mt][rr];
        }
    }

    rsl += __shfl_xor(rsl, 16); rsl += __shfl_xor(rsl, 32);
    rsp += __shfl_xor(rsp, 16); rsp += __shfl_xor(rsp, 32);
    if (l < 16) {
        const long rb = ((long)(b * nch + chunk) * NP + nt * 16 + l) * 2;
        rspart[rb + 0] = rsl;
        rspart[rb + 1] = rsp;
    }
    if (do_ts) {
        ts0 += __shfl_xor(ts0, 16); ts0 += __shfl_xor(ts0, 32);
        ts1 += __shfl_xor(ts1, 16); ts1 += __shfl_xor(ts1, 32);
        ts2 += __shfl_xor(ts2, 16); ts2 += __shfl_xor(ts2, 32);
        ts3 += __shfl_xor(ts3, 16); ts3 += __shfl_xor(ts3, 32);
        if (l < 16) {
            const long tb = (long)(b * nch + chunk) * MP;
            tspart[tb +  0 + l] = ts0;
            tspart[tb + 16 + l] = ts1;
            tspart[tb + 32 + l] = ts2;
            tspart[tb + 48 + l] = ts3;
        }
    }
}

// ============================ epilogue (shared) ==============================
__global__ __launch_bounds__(1024)
void matcher_epilogue(const float* __restrict__ pred_logits,
                      const float* __restrict__ pred_style,
                      const int*   __restrict__ styles,
                      const float* __restrict__ part1,
                      const float* __restrict__ part2,
                      const float* __restrict__ rspart,
                      const float* __restrict__ tspart,
                      float* __restrict__ out, int nch)
{
    __shared__ float red1[16][64], red2[16][64], redt[16][64];
    __shared__ float slw[16], spw[16];

    const int blk = blockIdx.x;
    const int b = blk / NQ, n = blk % NQ;
    const int t = threadIdx.x;
    const int m = t & 63, cg = t >> 6;

    float S1 = 0.f, S2 = 0.f, St = 0.f;
    for (int c = cg; c < nch; c += 16) {
        const long base = ((long)(b * nch + c) * NP + n) * MP + m;
        S1 += part1[base];
        S2 += part2[base];
        St += tspart[(long)(b * nch + c) * MP + m];
    }
    red1[cg][m] = S1; red2[cg][m] = S2; redt[cg][m] = St;

    float sl = 0.f, sp = 0.f;
    if (t < nch) {
        const float2 v = *(const float2*)&rspart[((long)(b * nch + t) * NP + n) * 2];
        sl = v.x; sp = v.y;
    }
    #pragma unroll
    for (int off = 32; off; off >>= 1) { sl += __shfl_down(sl, off); sp += __shfl_down(sp, off); }
    if ((t & 63) == 0) { slw[t >> 6] = sl; spw[t >> 6] = sp; }
    __syncthreads();

    if (t < MQ) {
        float Sl = 0.f, Sp = 0.f, s1 = 0.f, s2 = 0.f, st = 0.f;
        #pragma unroll
        for (int ww = 0; ww < 16; ww++) {
            Sl += slw[ww]; Sp += spw[ww];
            s1 += red1[ww][t]; s2 += red2[ww][t]; st += redt[ww][t];
        }

        const float l0 = pred_logits[(b * NQ + n) * 2 + 0];
        const float l1 = pred_logits[(b * NQ + n) * 2 + 1];
        const float p1 = 1.0f / (1.0f + __expf(l0 - l1));

        const float* stp = &pred_style[(b * NQ + n) * 4];
        const float v0 = stp[0], v1 = stp[1], v2 = stp[2], v3 = stp[3];
        const float mx = fmaxf(fmaxf(v0, v1), fmaxf(v2, v3));
        const float e0 = __expf(v0 - mx), e1 = __expf(v1 - mx),
                    e2 = __expf(v2 - mx), e3 = __expf(v3 - mx);
        const float esum = e0 + e1 + e2 + e3;
        int sid = styles[b * MQ + t];
        sid = min(max(sid, 0), 3);
        const float ps = (sid == 0 ? e0 : sid == 1 ? e1 : sid == 2 ? e2 : e3) / esum;

        const float cost_mask = -(s1 + Sl) * (1.0f / (float)HWSZ);
        const float dice = 1.0f - (2.0f * s2 + 1.0f) / (Sp + st + 1.0f);

        float c = 2.0f * (-p1) + 5.0f * cost_mask + 5.0f * dice + 1.0f * (-ps);
        if (isnan(c)) c = 10000.0f;
        else if (isinf(c)) c = (c > 0.f) ? 10000.0f : -10000.0f;
        out[(b * NQ + n) * MQ + t] = c;
    }
}

extern "C" void kernel_launch(void* const* d_in, const int* in_sizes, int n_in,
                              void* d_out, int out_size, void* d_ws, size_t ws_size,
                              hipStream_t stream) {
    const float* pred_logits = (const float*)d_in[0];
    const float* pred_masks  = (const float*)d_in[1];
    const float* pred_style  = (const float*)d_in[2];
    const float* tgt_masks   = (const float*)d_in[3];
    const int*   styles      = (const int*)d_in[4];
    float* out = (float*)d_out;

    const size_t packB_elems = (size_t)BQ * MQ * HWSZ;           // bf16 elems
    const size_t packB_bytes = packB_elems * 2;                  // 26.2 MB
    auto need = [](int c) {
        return (size_t)c * (2ull * BQ * NP * MP * 4ull
                            + (size_t)BQ * NP * 2 * 4ull
                            + (size_t)BQ * MP * 4ull);
    };

    int nch = 0; bool use_packed = false;
    for (int cand = 128; cand >= 64; cand >>= 1)
        if (need(cand) + packB_bytes <= ws_size) { nch = cand; use_packed = true; break; }
    if (!use_packed)
        for (int cand = 128; cand >= 8; cand >>= 1)
            if (need(cand) <= ws_size) { nch = cand; break; }
    const int Kc = HWSZ / nch;

    float* part1  = (float*)d_ws;
    float* part2  = part1 + (size_t)BQ * nch * NP * MP;
    float* rspart = part2 + (size_t)BQ * nch * NP * MP;
    float* tspart = rspart + (size_t)BQ * nch * NP * 2;
    unsigned short* bpack = (unsigned short*)(tspart + (size_t)BQ * nch * MP);

    if (use_packed) {
        pack_b<<<dim3(nch, BQ), 256, 0, stream>>>(tgt_masks, bpack, tspart, nch, Kc);
        matcher_main_packed<<<2 * BQ * nch, 256, 0, stream>>>(
            pred_masks, bpack, part1, part2, rspart, nch, Kc);
    } else {
        matcher_main<<<nch * 7, 256, 0, stream>>>(
            pred_masks, tgt_masks, part1, part2, rspart, tspart, nch, Kc);
    }

    matcher_epilogue<<<BQ * NQ, 1024, 0, stream>>>(
        pred_logits, pred_style, styles, part1, part2, rspart, tspart, out, nch);
}